// Round 1
// baseline (1050.442 us; speedup 1.0000x reference)
//
#include <hip/hip_runtime.h>
#include <hip/hip_bf16.h>

#define NN   100000
#define HIDD 128

// ---------------------------------------------------------------------------
// CSR build
// ---------------------------------------------------------------------------
__global__ void count_kernel(const int* __restrict__ edges, int n_edges,
                             int* __restrict__ cnt) {
    int e = blockIdx.x * blockDim.x + threadIdx.x;
    if (e >= n_edges) return;
    unsigned s = (unsigned)edges[e];
    unsigned d = (unsigned)edges[n_edges + e];
    if (s < NN && d < NN) atomicAdd(&cnt[d], 1);
}

__global__ void scan_kernel(const int* __restrict__ cnt, int* __restrict__ row_ptr,
                            int n) {
    __shared__ int lds[1024];
    int t = threadIdx.x;
    int seg = (n + 1023) >> 10;
    int b = t * seg;
    int e = min(n, b + seg);
    int s = 0;
    for (int i = b; i < e; ++i) s += cnt[i];
    lds[t] = s;
    __syncthreads();
    // Hillis-Steele inclusive scan over 1024 partials
    for (int off = 1; off < 1024; off <<= 1) {
        int v = (t >= off) ? lds[t - off] : 0;
        __syncthreads();
        lds[t] += v;
        __syncthreads();
    }
    int run = (t == 0) ? 0 : lds[t - 1];
    for (int i = b; i < e; ++i) { run += cnt[i]; row_ptr[i + 1] = run; }
    if (t == 0) row_ptr[0] = 0;
}

__global__ void fill_kernel(const int* __restrict__ edges, int n_edges,
                            const int* __restrict__ row_ptr,
                            int* __restrict__ cursor, int* __restrict__ col_src) {
    int e = blockIdx.x * blockDim.x + threadIdx.x;
    if (e >= n_edges) return;
    unsigned s = (unsigned)edges[e];
    unsigned d = (unsigned)edges[n_edges + e];
    if (s < NN && d < NN) {
        int pos = atomicAdd(&cursor[d], 1);
        col_src[row_ptr[d] + pos] = (int)s;
    }
}

// ---------------------------------------------------------------------------
// Pull-mode mean aggregation: one wave per node.
// ---------------------------------------------------------------------------
__global__ void aggregate128(const float* __restrict__ h,
                             const int* __restrict__ row_ptr,
                             const int* __restrict__ col_src,
                             float* __restrict__ aggr, int n_nodes) {
    int node = (int)((blockIdx.x * (size_t)blockDim.x + threadIdx.x) >> 6);
    int lane = threadIdx.x & 63;
    if (node >= n_nodes) return;
    int beg = row_ptr[node], end = row_ptr[node + 1];
    float ax = 0.f, ay = 0.f;
    for (int j = beg; j < end; ++j) {
        int s = col_src[j];
        const float2 v = *(const float2*)&h[(size_t)s * HIDD + lane * 2];
        ax += v.x; ay += v.y;
    }
    float inv = (end > beg) ? 1.0f / (float)(end - beg) : 0.0f;
    float2 o; o.x = ax * inv; o.y = ay * inv;
    *(float2*)&aggr[(size_t)node * HIDD + lane * 2] = o;
}

__global__ void aggregate32(const float* __restrict__ x,
                            const int* __restrict__ row_ptr,
                            const int* __restrict__ col_src,
                            float* __restrict__ aggr, int n_nodes) {
    int node = (int)((blockIdx.x * (size_t)blockDim.x + threadIdx.x) >> 6);
    int lane = threadIdx.x & 63;
    if (node >= n_nodes) return;
    int beg = row_ptr[node], end = row_ptr[node + 1];
    if (lane < 32) {
        float a = 0.f;
        for (int j = beg; j < end; ++j) {
            int s = col_src[j];
            a += x[(size_t)s * 32 + lane];
        }
        float inv = (end > beg) ? 1.0f / (float)(end - beg) : 0.0f;
        aggr[(size_t)node * 32 + lane] = a * inv;
    }
}

// ---------------------------------------------------------------------------
// Fused dual GEMM: out[n][o] = maybe_relu( sum_k inA[n][k]*WA[o][k]
//                                        + sum_k inB[n][k]*WB[o][k] + bias[o] )
// Tile 128 rows x 128 cols, 256 threads, 8x8 outputs/thread, K-chunk 16.
// MEAN: accumulate column sums of out into gsum (no store of out).
// ---------------------------------------------------------------------------
template <int KA, bool RELU, bool MEAN>
__global__ __launch_bounds__(256)
void gemm_fused(const float* __restrict__ inA, const float* __restrict__ inB,
                const float* __restrict__ WA, const float* __restrict__ WB,
                const float* __restrict__ bias,
                float* __restrict__ out, float* __restrict__ gsum, int n_nodes) {
    __shared__ float SA[16][132];
    __shared__ float SW[16][132];
    __shared__ float gl[128];

    const int t = threadIdx.x;
    const int rowbase = blockIdx.x * 128;
    const int trow = t >> 4, tcol = t & 15;
    const int r0 = trow * 8, c0 = tcol * 8;

    float acc[8][8];
#pragma unroll
    for (int i = 0; i < 8; ++i)
#pragma unroll
        for (int j = 0; j < 8; ++j) acc[i][j] = 0.f;

    const int ldrow = t >> 1;        // 0..127
    const int ldkb  = (t & 1) * 8;   // 0 or 8

    for (int op = 0; op < 2; ++op) {
        const float* __restrict__ in = op ? inB : inA;
        const float* __restrict__ W  = op ? WB : WA;
        for (int k0 = 0; k0 < KA; k0 += 16) {
            __syncthreads();  // protect LDS reuse from previous chunk
            {
                int grow = rowbase + ldrow;
                float4 v0 = make_float4(0.f, 0.f, 0.f, 0.f);
                float4 v1 = make_float4(0.f, 0.f, 0.f, 0.f);
                if (grow < n_nodes) {
                    const float* p = &in[(size_t)grow * KA + k0 + ldkb];
                    v0 = *(const float4*)p;
                    v1 = *(const float4*)(p + 4);
                }
                SA[ldkb + 0][ldrow] = v0.x; SA[ldkb + 1][ldrow] = v0.y;
                SA[ldkb + 2][ldrow] = v0.z; SA[ldkb + 3][ldrow] = v0.w;
                SA[ldkb + 4][ldrow] = v1.x; SA[ldkb + 5][ldrow] = v1.y;
                SA[ldkb + 6][ldrow] = v1.z; SA[ldkb + 7][ldrow] = v1.w;

                const float* q = &W[(size_t)ldrow * KA + k0 + ldkb];
                float4 w0 = *(const float4*)q;
                float4 w1 = *(const float4*)(q + 4);
                SW[ldkb + 0][ldrow] = w0.x; SW[ldkb + 1][ldrow] = w0.y;
                SW[ldkb + 2][ldrow] = w0.z; SW[ldkb + 3][ldrow] = w0.w;
                SW[ldkb + 4][ldrow] = w1.x; SW[ldkb + 5][ldrow] = w1.y;
                SW[ldkb + 6][ldrow] = w1.z; SW[ldkb + 7][ldrow] = w1.w;
            }
            __syncthreads();
#pragma unroll
            for (int kk = 0; kk < 16; ++kk) {
                float4 a0 = *(const float4*)&SA[kk][r0];
                float4 a1 = *(const float4*)&SA[kk][r0 + 4];
                float4 w0 = *(const float4*)&SW[kk][c0];
                float4 w1 = *(const float4*)&SW[kk][c0 + 4];
                float av[8] = {a0.x, a0.y, a0.z, a0.w, a1.x, a1.y, a1.z, a1.w};
                float wv[8] = {w0.x, w0.y, w0.z, w0.w, w1.x, w1.y, w1.z, w1.w};
#pragma unroll
                for (int i = 0; i < 8; ++i)
#pragma unroll
                    for (int j = 0; j < 8; ++j)
                        acc[i][j] = fmaf(av[i], wv[j], acc[i][j]);
            }
        }
    }

    float bv[8];
#pragma unroll
    for (int j = 0; j < 8; ++j) bv[j] = bias[c0 + j];

    if (!MEAN) {
#pragma unroll
        for (int i = 0; i < 8; ++i) {
            int grow = rowbase + r0 + i;
            if (grow >= n_nodes) continue;
            float4 v0, v1;
            float o0 = acc[i][0] + bv[0], o1 = acc[i][1] + bv[1];
            float o2 = acc[i][2] + bv[2], o3 = acc[i][3] + bv[3];
            float o4 = acc[i][4] + bv[4], o5 = acc[i][5] + bv[5];
            float o6 = acc[i][6] + bv[6], o7 = acc[i][7] + bv[7];
            if (RELU) {
                o0 = fmaxf(o0, 0.f); o1 = fmaxf(o1, 0.f); o2 = fmaxf(o2, 0.f);
                o3 = fmaxf(o3, 0.f); o4 = fmaxf(o4, 0.f); o5 = fmaxf(o5, 0.f);
                o6 = fmaxf(o6, 0.f); o7 = fmaxf(o7, 0.f);
            }
            v0.x = o0; v0.y = o1; v0.z = o2; v0.w = o3;
            v1.x = o4; v1.y = o5; v1.z = o6; v1.w = o7;
            *(float4*)&out[(size_t)grow * HIDD + c0]     = v0;
            *(float4*)&out[(size_t)grow * HIDD + c0 + 4] = v1;
        }
    } else {
        if (t < 128) gl[t] = 0.f;
        __syncthreads();
#pragma unroll
        for (int j = 0; j < 8; ++j) {
            float s = 0.f;
#pragma unroll
            for (int i = 0; i < 8; ++i) {
                int grow = rowbase + r0 + i;
                if (grow < n_nodes) s += acc[i][j] + bv[j];
            }
            atomicAdd(&gl[c0 + j], s);
        }
        __syncthreads();
        if (t < 128) atomicAdd(&gsum[t], gl[t]);
    }
}

// ---------------------------------------------------------------------------
// Heads: g = gsum/N; logits = relu(g@Pw1.T+Pb1)@Pw2.T+Pb2; value likewise.
// ---------------------------------------------------------------------------
__global__ void heads_kernel(const float* __restrict__ gsum,
                             const float* __restrict__ Pw1, const float* __restrict__ Pb1,
                             const float* __restrict__ Pw2, const float* __restrict__ Pb2,
                             const float* __restrict__ Vw1, const float* __restrict__ Vb1,
                             const float* __restrict__ Vw2, const float* __restrict__ Vb2,
                             float* __restrict__ out, float inv_n) {
    __shared__ float g[128], a1[128], v1[128];
    int t = threadIdx.x;
    if (t < 128) g[t] = gsum[t] * inv_n;
    __syncthreads();
    if (t < 128) {
        float s = Pb1[t];
        for (int f = 0; f < 128; ++f) s = fmaf(Pw1[t * 128 + f], g[f], s);
        a1[t] = fmaxf(s, 0.f);
    } else {
        int o = t - 128;
        float s = Vb1[o];
        for (int f = 0; f < 128; ++f) s = fmaf(Vw1[o * 128 + f], g[f], s);
        v1[o] = fmaxf(s, 0.f);
    }
    __syncthreads();
    if (t < 6) {
        float s = Pb2[t];
        for (int f = 0; f < 128; ++f) s = fmaf(Pw2[t * 128 + f], a1[f], s);
        out[t] = s;
    }
    if (t == 6) {
        float s = Vb2[0];
        for (int f = 0; f < 128; ++f) s = fmaf(Vw2[f], v1[f], s);
        out[6] = s;
    }
}

// ---------------------------------------------------------------------------
extern "C" void kernel_launch(void* const* d_in, const int* in_sizes, int n_in,
                              void* d_out, int out_size, void* d_ws, size_t ws_size,
                              hipStream_t stream) {
    const float* x    = (const float*)d_in[0];
    const int*   edges = (const int*)d_in[1];
    const float* W1l = (const float*)d_in[2];
    const float* b1  = (const float*)d_in[3];
    const float* W1r = (const float*)d_in[4];
    const float* W2l = (const float*)d_in[5];
    const float* b2  = (const float*)d_in[6];
    const float* W2r = (const float*)d_in[7];
    const float* W3l = (const float*)d_in[8];
    const float* b3  = (const float*)d_in[9];
    const float* W3r = (const float*)d_in[10];
    const float* Pw1 = (const float*)d_in[11];
    const float* Pb1 = (const float*)d_in[12];
    const float* Pw2 = (const float*)d_in[13];
    const float* Pb2 = (const float*)d_in[14];
    const float* Vw1 = (const float*)d_in[15];
    const float* Vb1 = (const float*)d_in[16];
    const float* Vw2 = (const float*)d_in[17];
    const float* Vb2 = (const float*)d_in[18];
    float* outp = (float*)d_out;

    const int E = in_sizes[1] / 2;

    // ---- workspace layout (element offsets, each region 256B-aligned) ----
    // [cnt N][cursor N][gsum 128pad] <- zeroed each call
    // [row_ptr N+1][col_src E][aggr N*128][hA N*128][hB N*128]
    int*   ws_i = (int*)d_ws;
    float* ws_f = (float*)d_ws;
    size_t o_cnt    = 0;
    size_t o_cursor = NN;
    size_t o_gsum   = 2 * (size_t)NN;                  // 128 floats (zeroed)
    size_t o_rowptr = 2 * (size_t)NN + 192;
    size_t o_col    = o_rowptr + ((NN + 1 + 63) / 64) * 64;
    size_t o_aggr   = ((o_col + (size_t)E + 63) / 64) * 64;
    size_t o_hA     = o_aggr + (size_t)NN * HIDD;
    size_t o_hB     = o_hA + (size_t)NN * HIDD;

    int*   cnt     = ws_i + o_cnt;
    int*   cursor  = ws_i + o_cursor;
    float* gsum    = ws_f + o_gsum;
    int*   row_ptr = ws_i + o_rowptr;
    int*   col_src = ws_i + o_col;
    float* aggr    = ws_f + o_aggr;
    float* hA      = ws_f + o_hA;
    float* hB      = ws_f + o_hB;

    // zero cnt, cursor, gsum in one shot
    hipMemsetAsync(d_ws, 0, (2 * (size_t)NN + 128) * sizeof(int), stream);

    const int TB = 256;
    dim3 blk(TB);
    dim3 grid_e((E + TB - 1) / TB);
    dim3 grid_n((NN + 3) / 4);          // 4 waves (nodes) per 256-thread block
    dim3 grid_g((NN + 127) / 128);      // GEMM row tiles

    // CSR build (reused by all 3 layers)
    count_kernel<<<grid_e, blk, 0, stream>>>(edges, E, cnt);
    scan_kernel<<<1, 1024, 0, stream>>>(cnt, row_ptr, NN);
    fill_kernel<<<grid_e, blk, 0, stream>>>(edges, E, row_ptr, cursor, col_src);

    // Layer 1 (K=32, relu)
    aggregate32<<<grid_n, blk, 0, stream>>>(x, row_ptr, col_src, aggr, NN);
    gemm_fused<32, true, false><<<grid_g, blk, 0, stream>>>(
        aggr, x, W1l, W1r, b1, hA, nullptr, NN);

    // Layer 2 (K=128, relu)
    aggregate128<<<grid_n, blk, 0, stream>>>(hA, row_ptr, col_src, aggr, NN);
    gemm_fused<128, true, false><<<grid_g, blk, 0, stream>>>(
        aggr, hA, W2l, W2r, b2, hB, nullptr, NN);

    // Layer 3 (K=128, no relu, fused column-mean into gsum)
    aggregate128<<<grid_n, blk, 0, stream>>>(hB, row_ptr, col_src, aggr, NN);
    gemm_fused<128, false, true><<<grid_g, blk, 0, stream>>>(
        aggr, hB, W3l, W3r, b3, nullptr, gsum, NN);

    // Heads
    heads_kernel<<<1, 256, 0, stream>>>(gsum, Pw1, Pb1, Pw2, Pb2,
                                        Vw1, Vb1, Vw2, Vb2, outp,
                                        1.0f / (float)NN);
}

// Round 2
// 701.115 us; speedup vs baseline: 1.4982x; 1.4982x over previous
//
#include <hip/hip_runtime.h>
#include <hip/hip_bf16.h>

#define NN   100000
#define HIDD 128

// ---------------------------------------------------------------------------
// CSR build
// ---------------------------------------------------------------------------
__global__ void count_kernel(const int* __restrict__ edges, int n_edges,
                             int* __restrict__ cnt) {
    int e = blockIdx.x * blockDim.x + threadIdx.x;
    if (e >= n_edges) return;
    unsigned s = (unsigned)edges[e];
    unsigned d = (unsigned)edges[n_edges + e];
    if (s < NN && d < NN) atomicAdd(&cnt[d], 1);
}

// Device-wide exclusive-scan in 3 stages.
// Stage A: per-block (1024 items) inclusive scan, coalesced int4 loads.
//          partial may ALIAS cnt (each index is read-then-written by the
//          same thread; no cross-thread overlap).
__global__ __launch_bounds__(256)
void scan_blocks(const int* __restrict__ cnt, int* __restrict__ partial,
                 int* __restrict__ bsums, int n) {
    __shared__ int lds[256];
    int t = threadIdx.x;
    int base = blockIdx.x * 1024 + t * 4;
    int v0 = 0, v1 = 0, v2 = 0, v3 = 0;
    if (base + 3 < n) {
        int4 v = *(const int4*)&cnt[base];
        v0 = v.x; v1 = v.y; v2 = v.z; v3 = v.w;
    } else {
        if (base + 0 < n) v0 = cnt[base + 0];
        if (base + 1 < n) v1 = cnt[base + 1];
        if (base + 2 < n) v2 = cnt[base + 2];
    }
    lds[t] = v0 + v1 + v2 + v3;
    __syncthreads();
    for (int off = 1; off < 256; off <<= 1) {
        int u = (t >= off) ? lds[t - off] : 0;
        __syncthreads();
        lds[t] += u;
        __syncthreads();
    }
    int excl = (t == 0) ? 0 : lds[t - 1];
    int i0 = excl + v0, i1 = i0 + v1, i2 = i1 + v2, i3 = i2 + v3;
    if (base + 0 < n) partial[base + 0] = i0;
    if (base + 1 < n) partial[base + 1] = i1;
    if (base + 2 < n) partial[base + 2] = i2;
    if (base + 3 < n) partial[base + 3] = i3;
    if (t == 255) bsums[blockIdx.x] = lds[255];
}

// Stage B: scan the (<=128) block sums in one small block.
__global__ void scan_bsums(int* __restrict__ bsums, int nb) {
    __shared__ int lds[128];
    int t = threadIdx.x;
    lds[t] = (t < nb) ? bsums[t] : 0;
    __syncthreads();
    for (int off = 1; off < 128; off <<= 1) {
        int u = (t >= off) ? lds[t - off] : 0;
        __syncthreads();
        lds[t] += u;
        __syncthreads();
    }
    if (t < nb) bsums[t] = lds[t];
}

// Stage C: add block offsets, emit row_ptr (row_ptr[0]=0, row_ptr[i+1]=incl[i]).
__global__ void finalize_rowptr(const int* __restrict__ partial,
                                const int* __restrict__ bsums,
                                int* __restrict__ row_ptr, int n) {
    int i = blockIdx.x * blockDim.x + threadIdx.x;
    if (i < n) {
        int b = i >> 10;
        int off = (b > 0) ? bsums[b - 1] : 0;
        row_ptr[i + 1] = partial[i] + off;
    }
    if (i == 0) row_ptr[0] = 0;
}

__global__ void fill_kernel(const int* __restrict__ edges, int n_edges,
                            const int* __restrict__ row_ptr,
                            int* __restrict__ cursor, int* __restrict__ col_src) {
    int e = blockIdx.x * blockDim.x + threadIdx.x;
    if (e >= n_edges) return;
    unsigned s = (unsigned)edges[e];
    unsigned d = (unsigned)edges[n_edges + e];
    if (s < NN && d < NN) {
        int pos = atomicAdd(&cursor[d], 1);
        col_src[row_ptr[d] + pos] = (int)s;
    }
}

// ---------------------------------------------------------------------------
// Pull-mode mean aggregation: one wave per node, neighbor loop unrolled x4
// for memory-level parallelism (4 outstanding gathers per lane).
// ---------------------------------------------------------------------------
__global__ void aggregate128(const float* __restrict__ h,
                             const int* __restrict__ row_ptr,
                             const int* __restrict__ col_src,
                             float* __restrict__ aggr, int n_nodes) {
    int node = (int)((blockIdx.x * (size_t)blockDim.x + threadIdx.x) >> 6);
    int lane = threadIdx.x & 63;
    if (node >= n_nodes) return;
    int beg = row_ptr[node], end = row_ptr[node + 1];
    float ax = 0.f, ay = 0.f;
    int j = beg;
    for (; j + 4 <= end; j += 4) {
        int s0 = col_src[j], s1 = col_src[j + 1];
        int s2 = col_src[j + 2], s3 = col_src[j + 3];
        float2 v0 = *(const float2*)&h[(size_t)s0 * HIDD + lane * 2];
        float2 v1 = *(const float2*)&h[(size_t)s1 * HIDD + lane * 2];
        float2 v2 = *(const float2*)&h[(size_t)s2 * HIDD + lane * 2];
        float2 v3 = *(const float2*)&h[(size_t)s3 * HIDD + lane * 2];
        ax += (v0.x + v1.x) + (v2.x + v3.x);
        ay += (v0.y + v1.y) + (v2.y + v3.y);
    }
    for (; j < end; ++j) {
        int s = col_src[j];
        float2 v = *(const float2*)&h[(size_t)s * HIDD + lane * 2];
        ax += v.x; ay += v.y;
    }
    float inv = (end > beg) ? 1.0f / (float)(end - beg) : 0.0f;
    float2 o; o.x = ax * inv; o.y = ay * inv;
    *(float2*)&aggr[(size_t)node * HIDD + lane * 2] = o;
}

__global__ void aggregate32(const float* __restrict__ x,
                            const int* __restrict__ row_ptr,
                            const int* __restrict__ col_src,
                            float* __restrict__ aggr, int n_nodes) {
    int node = (int)((blockIdx.x * (size_t)blockDim.x + threadIdx.x) >> 5);
    int lane = threadIdx.x & 31;
    if (node >= n_nodes) return;
    int beg = row_ptr[node], end = row_ptr[node + 1];
    float a = 0.f;
    int j = beg;
    for (; j + 4 <= end; j += 4) {
        int s0 = col_src[j], s1 = col_src[j + 1];
        int s2 = col_src[j + 2], s3 = col_src[j + 3];
        float u0 = x[(size_t)s0 * 32 + lane];
        float u1 = x[(size_t)s1 * 32 + lane];
        float u2 = x[(size_t)s2 * 32 + lane];
        float u3 = x[(size_t)s3 * 32 + lane];
        a += (u0 + u1) + (u2 + u3);
    }
    for (; j < end; ++j) a += x[(size_t)col_src[j] * 32 + lane];
    float inv = (end > beg) ? 1.0f / (float)(end - beg) : 0.0f;
    aggr[(size_t)node * 32 + lane] = a * inv;
}

// ---------------------------------------------------------------------------
// Fused dual GEMM: out[n][o] = maybe_relu( sum_k inA[n][k]*WA[o][k]
//                                        + sum_k inB[n][k]*WB[o][k] + bias[o] )
// Tile 128 rows x 128 cols, 256 threads, 8x8 outputs/thread, K-chunk 16.
// MEAN: accumulate column sums of out into gsum (no store of out).
// ---------------------------------------------------------------------------
template <int KA, bool RELU, bool MEAN>
__global__ __launch_bounds__(256)
void gemm_fused(const float* __restrict__ inA, const float* __restrict__ inB,
                const float* __restrict__ WA, const float* __restrict__ WB,
                const float* __restrict__ bias,
                float* __restrict__ out, float* __restrict__ gsum, int n_nodes) {
    __shared__ float SA[16][132];
    __shared__ float SW[16][132];
    __shared__ float gl[128];

    const int t = threadIdx.x;
    const int rowbase = blockIdx.x * 128;
    const int trow = t >> 4, tcol = t & 15;
    const int r0 = trow * 8, c0 = tcol * 8;

    float acc[8][8];
#pragma unroll
    for (int i = 0; i < 8; ++i)
#pragma unroll
        for (int j = 0; j < 8; ++j) acc[i][j] = 0.f;

    const int ldrow = t >> 1;        // 0..127
    const int ldkb  = (t & 1) * 8;   // 0 or 8

    for (int op = 0; op < 2; ++op) {
        const float* __restrict__ in = op ? inB : inA;
        const float* __restrict__ W  = op ? WB : WA;
        for (int k0 = 0; k0 < KA; k0 += 16) {
            __syncthreads();  // protect LDS reuse from previous chunk
            {
                int grow = rowbase + ldrow;
                float4 v0 = make_float4(0.f, 0.f, 0.f, 0.f);
                float4 v1 = make_float4(0.f, 0.f, 0.f, 0.f);
                if (grow < n_nodes) {
                    const float* p = &in[(size_t)grow * KA + k0 + ldkb];
                    v0 = *(const float4*)p;
                    v1 = *(const float4*)(p + 4);
                }
                SA[ldkb + 0][ldrow] = v0.x; SA[ldkb + 1][ldrow] = v0.y;
                SA[ldkb + 2][ldrow] = v0.z; SA[ldkb + 3][ldrow] = v0.w;
                SA[ldkb + 4][ldrow] = v1.x; SA[ldkb + 5][ldrow] = v1.y;
                SA[ldkb + 6][ldrow] = v1.z; SA[ldkb + 7][ldrow] = v1.w;

                const float* q = &W[(size_t)ldrow * KA + k0 + ldkb];
                float4 w0 = *(const float4*)q;
                float4 w1 = *(const float4*)(q + 4);
                SW[ldkb + 0][ldrow] = w0.x; SW[ldkb + 1][ldrow] = w0.y;
                SW[ldkb + 2][ldrow] = w0.z; SW[ldkb + 3][ldrow] = w0.w;
                SW[ldkb + 4][ldrow] = w1.x; SW[ldkb + 5][ldrow] = w1.y;
                SW[ldkb + 6][ldrow] = w1.z; SW[ldkb + 7][ldrow] = w1.w;
            }
            __syncthreads();
#pragma unroll
            for (int kk = 0; kk < 16; ++kk) {
                float4 a0 = *(const float4*)&SA[kk][r0];
                float4 a1 = *(const float4*)&SA[kk][r0 + 4];
                float4 w0 = *(const float4*)&SW[kk][c0];
                float4 w1 = *(const float4*)&SW[kk][c0 + 4];
                float av[8] = {a0.x, a0.y, a0.z, a0.w, a1.x, a1.y, a1.z, a1.w};
                float wv[8] = {w0.x, w0.y, w0.z, w0.w, w1.x, w1.y, w1.z, w1.w};
#pragma unroll
                for (int i = 0; i < 8; ++i)
#pragma unroll
                    for (int j = 0; j < 8; ++j)
                        acc[i][j] = fmaf(av[i], wv[j], acc[i][j]);
            }
        }
    }

    float bv[8];
#pragma unroll
    for (int j = 0; j < 8; ++j) bv[j] = bias[c0 + j];

    if (!MEAN) {
#pragma unroll
        for (int i = 0; i < 8; ++i) {
            int grow = rowbase + r0 + i;
            if (grow >= n_nodes) continue;
            float4 v0, v1;
            float o0 = acc[i][0] + bv[0], o1 = acc[i][1] + bv[1];
            float o2 = acc[i][2] + bv[2], o3 = acc[i][3] + bv[3];
            float o4 = acc[i][4] + bv[4], o5 = acc[i][5] + bv[5];
            float o6 = acc[i][6] + bv[6], o7 = acc[i][7] + bv[7];
            if (RELU) {
                o0 = fmaxf(o0, 0.f); o1 = fmaxf(o1, 0.f); o2 = fmaxf(o2, 0.f);
                o3 = fmaxf(o3, 0.f); o4 = fmaxf(o4, 0.f); o5 = fmaxf(o5, 0.f);
                o6 = fmaxf(o6, 0.f); o7 = fmaxf(o7, 0.f);
            }
            v0.x = o0; v0.y = o1; v0.z = o2; v0.w = o3;
            v1.x = o4; v1.y = o5; v1.z = o6; v1.w = o7;
            *(float4*)&out[(size_t)grow * HIDD + c0]     = v0;
            *(float4*)&out[(size_t)grow * HIDD + c0 + 4] = v1;
        }
    } else {
        if (t < 128) gl[t] = 0.f;
        __syncthreads();
#pragma unroll
        for (int j = 0; j < 8; ++j) {
            float s = 0.f;
#pragma unroll
            for (int i = 0; i < 8; ++i) {
                int grow = rowbase + r0 + i;
                if (grow < n_nodes) s += acc[i][j] + bv[j];
            }
            atomicAdd(&gl[c0 + j], s);
        }
        __syncthreads();
        if (t < 128) atomicAdd(&gsum[t], gl[t]);
    }
}

// ---------------------------------------------------------------------------
// Heads: g = gsum/N; logits = relu(g@Pw1.T+Pb1)@Pw2.T+Pb2; value likewise.
// ---------------------------------------------------------------------------
__global__ void heads_kernel(const float* __restrict__ gsum,
                             const float* __restrict__ Pw1, const float* __restrict__ Pb1,
                             const float* __restrict__ Pw2, const float* __restrict__ Pb2,
                             const float* __restrict__ Vw1, const float* __restrict__ Vb1,
                             const float* __restrict__ Vw2, const float* __restrict__ Vb2,
                             float* __restrict__ out, float inv_n) {
    __shared__ float g[128], a1[128], v1[128];
    int t = threadIdx.x;
    if (t < 128) g[t] = gsum[t] * inv_n;
    __syncthreads();
    if (t < 128) {
        float s = Pb1[t];
        for (int f = 0; f < 128; ++f) s = fmaf(Pw1[t * 128 + f], g[f], s);
        a1[t] = fmaxf(s, 0.f);
    } else {
        int o = t - 128;
        float s = Vb1[o];
        for (int f = 0; f < 128; ++f) s = fmaf(Vw1[o * 128 + f], g[f], s);
        v1[o] = fmaxf(s, 0.f);
    }
    __syncthreads();
    if (t < 6) {
        float s = Pb2[t];
        for (int f = 0; f < 128; ++f) s = fmaf(Pw2[t * 128 + f], a1[f], s);
        out[t] = s;
    }
    if (t == 6) {
        float s = Vb2[0];
        for (int f = 0; f < 128; ++f) s = fmaf(Vw2[f], v1[f], s);
        out[6] = s;
    }
}

// ---------------------------------------------------------------------------
extern "C" void kernel_launch(void* const* d_in, const int* in_sizes, int n_in,
                              void* d_out, int out_size, void* d_ws, size_t ws_size,
                              hipStream_t stream) {
    const float* x    = (const float*)d_in[0];
    const int*   edges = (const int*)d_in[1];
    const float* W1l = (const float*)d_in[2];
    const float* b1  = (const float*)d_in[3];
    const float* W1r = (const float*)d_in[4];
    const float* W2l = (const float*)d_in[5];
    const float* b2  = (const float*)d_in[6];
    const float* W2r = (const float*)d_in[7];
    const float* W3l = (const float*)d_in[8];
    const float* b3  = (const float*)d_in[9];
    const float* W3r = (const float*)d_in[10];
    const float* Pw1 = (const float*)d_in[11];
    const float* Pb1 = (const float*)d_in[12];
    const float* Pw2 = (const float*)d_in[13];
    const float* Pb2 = (const float*)d_in[14];
    const float* Vw1 = (const float*)d_in[15];
    const float* Vb1 = (const float*)d_in[16];
    const float* Vw2 = (const float*)d_in[17];
    const float* Vb2 = (const float*)d_in[18];
    float* outp = (float*)d_out;

    const int E = in_sizes[1] / 2;

    // ---- workspace layout (element offsets) ----
    // [cnt N (aliased as scan partial)][cursor N][gsum 128f][bsums 128i]
    // [row_ptr N+1][col_src E][aggr N*128][hA N*128][hB N*128]
    int*   ws_i = (int*)d_ws;
    float* ws_f = (float*)d_ws;
    size_t o_cnt    = 0;
    size_t o_cursor = NN;
    size_t o_gsum   = 2 * (size_t)NN;          // 128 floats (zeroed by memset)
    size_t o_bsums  = 2 * (size_t)NN + 128;    // 128 ints
    size_t o_rowptr = 2 * (size_t)NN + 256;
    size_t o_col    = o_rowptr + ((NN + 1 + 63) / 64) * 64;
    size_t o_aggr   = ((o_col + (size_t)E + 63) / 64) * 64;
    size_t o_hA     = o_aggr + (size_t)NN * HIDD;
    size_t o_hB     = o_hA + (size_t)NN * HIDD;

    int*   cnt     = ws_i + o_cnt;
    int*   cursor  = ws_i + o_cursor;
    float* gsum    = ws_f + o_gsum;
    int*   bsums   = ws_i + o_bsums;
    int*   row_ptr = ws_i + o_rowptr;
    int*   col_src = ws_i + o_col;
    float* aggr    = ws_f + o_aggr;
    float* hA      = ws_f + o_hA;
    float* hB      = ws_f + o_hB;

    // zero cnt, cursor, gsum in one shot
    hipMemsetAsync(d_ws, 0, (2 * (size_t)NN + 128) * sizeof(int), stream);

    const int TB = 256;
    dim3 blk(TB);
    dim3 grid_e((E + TB - 1) / TB);
    dim3 grid_n64(((size_t)NN * 64 + TB - 1) / TB);  // 1 wave per node
    dim3 grid_n32(((size_t)NN * 32 + TB - 1) / TB);  // 32 threads per node
    dim3 grid_g((NN + 127) / 128);                   // GEMM row tiles

    // CSR build (reused by all 3 layers)
    count_kernel<<<grid_e, blk, 0, stream>>>(edges, E, cnt);
    const int nb_scan = (NN + 1023) / 1024;          // 98 <= 128
    scan_blocks<<<nb_scan, blk, 0, stream>>>(cnt, cnt /*alias ok*/, bsums, NN);
    scan_bsums<<<1, 128, 0, stream>>>(bsums, nb_scan);
    finalize_rowptr<<<(NN + TB - 1) / TB, blk, 0, stream>>>(cnt, bsums, row_ptr, NN);
    fill_kernel<<<grid_e, blk, 0, stream>>>(edges, E, row_ptr, cursor, col_src);

    // Layer 1 (K=32, relu)
    aggregate32<<<grid_n32, blk, 0, stream>>>(x, row_ptr, col_src, aggr, NN);
    gemm_fused<32, true, false><<<grid_g, blk, 0, stream>>>(
        aggr, x, W1l, W1r, b1, hA, nullptr, NN);

    // Layer 2 (K=128, relu)
    aggregate128<<<grid_n64, blk, 0, stream>>>(hA, row_ptr, col_src, aggr, NN);
    gemm_fused<128, true, false><<<grid_g, blk, 0, stream>>>(
        aggr, hA, W2l, W2r, b2, hB, nullptr, NN);

    // Layer 3 (K=128, no relu, fused column-mean into gsum)
    aggregate128<<<grid_n64, blk, 0, stream>>>(hB, row_ptr, col_src, aggr, NN);
    gemm_fused<128, false, true><<<grid_g, blk, 0, stream>>>(
        aggr, hB, W3l, W3r, b3, nullptr, gsum, NN);

    // Heads
    heads_kernel<<<1, 256, 0, stream>>>(gsum, Pw1, Pb1, Pw2, Pb2,
                                        Vw1, Vb1, Vw2, Vb2, outp,
                                        1.0f / (float)NN);
}